// Round 15
// baseline (36825.034 us; speedup 1.0000x reference)
//
#include <hip/hip_runtime.h>
#include <hip/hip_bf16.h>

#define B_    512
#define T_    256
#define INCH  32
#define C_    256

typedef float f32x4 __attribute__((ext_vector_type(4)));

__global__ void sentinel_kernel(float* __restrict__ out, int n, float v) {
  for (int i = blockIdx.x * blockDim.x + threadIdx.x; i < n;
       i += gridDim.x * blockDim.x)
    out[i] = v;
}

// Verified f32 transcription of the reference; FLOAT32 output (the fix).
// 128 blocks x 512 threads; block owns 4 batch rows. Thread computes gates
// g0=2*tid, g0+1 for all 4 rows. h/c live in LDS across enc->dec phases.
__global__ __launch_bounds__(512) void tae_f32(
    const float* __restrict__ x,
    const float* __restrict__ w_enc, const float* __restrict__ b_enc,
    const float* __restrict__ wih_e, const float* __restrict__ whh_e,
    const float* __restrict__ bih_e, const float* __restrict__ bhh_e,
    const float* __restrict__ wih_d, const float* __restrict__ whh_d,
    const float* __restrict__ bih_d, const float* __restrict__ bhh_d,
    const float* __restrict__ w_dec, const float* __restrict__ b_dec,
    float* __restrict__ out)
{
  const int b0   = blockIdx.x * 4;
  const int tid  = threadIdx.x;
  const int g0   = tid * 2;
  const int type = g0 >> 8;          // torch gate order: 0=i 1=f 2=g 3=o

  __shared__ __align__(16) float hs[2][4][256];
  __shared__ __align__(16) float cs[4][256];
  __shared__ __align__(16) float xe[4][256];
  __shared__ __align__(16) float gsm[4][4][256];

  for (int i = tid; i < 1024; i += 512) {
    ((float*)hs)[i] = 0.f;
    ((float*)cs)[i] = 0.f;
  }
  __syncthreads();

  const float brE[2] = { bih_e[g0] + bhh_e[g0], bih_e[g0 + 1] + bhh_e[g0 + 1] };
  int pb = 0;

  // ---------------- encoder ----------------
  for (int t = 0; t < T_; ++t) {
    #pragma unroll
    for (int u = 0; u < 2; ++u) {
      int item = g0 + u;
      int row = item >> 8, c = item & 255;
      const f32x4* wr = (const f32x4*)(w_enc + (size_t)c * INCH);
      const f32x4* xr = (const f32x4*)(x + ((size_t)(b0 + row) * T_ + t) * INCH);
      f32x4 a = {0.f, 0.f, 0.f, 0.f};
      #pragma unroll
      for (int q = 0; q < 8; ++q) a += wr[q] * xr[q];
      xe[row][c] = b_enc[c] + a[0] + a[1] + a[2] + a[3];
    }
    __syncthreads();

    f32x4 acc[2][4];
    #pragma unroll
    for (int u = 0; u < 2; ++u)
      #pragma unroll
      for (int row = 0; row < 4; ++row) acc[u][row] = (f32x4){0.f, 0.f, 0.f, 0.f};
    for (int k = 0; k < C_; k += 4) {
      f32x4 wx0 = *(const f32x4*)(wih_e + (size_t)g0 * C_ + k);
      f32x4 wx1 = *(const f32x4*)(wih_e + (size_t)(g0 + 1) * C_ + k);
      f32x4 wh0 = *(const f32x4*)(whh_e + (size_t)g0 * C_ + k);
      f32x4 wh1 = *(const f32x4*)(whh_e + (size_t)(g0 + 1) * C_ + k);
      #pragma unroll
      for (int row = 0; row < 4; ++row) {
        f32x4 xv = *(const f32x4*)(&xe[row][k]);
        f32x4 hv = *(const f32x4*)(&hs[pb][row][k]);
        acc[0][row] += wx0 * xv + wh0 * hv;
        acc[1][row] += wx1 * xv + wh1 * hv;
      }
    }
    #pragma unroll
    for (int u = 0; u < 2; ++u)
      #pragma unroll
      for (int row = 0; row < 4; ++row) {
        f32x4 a = acc[u][row];
        gsm[type][row][(g0 + u) & 255] = brE[u] + a[0] + a[1] + a[2] + a[3];
      }
    __syncthreads();

    if (tid < 128) {
      int row = tid >> 5, jb = tid & 31;
      #pragma unroll
      for (int v = 0; v < 8; ++v) {
        int j = jb * 8 + v;
        float iv = 1.f / (1.f + expf(-gsm[0][row][j]));
        float fv = 1.f / (1.f + expf(-gsm[1][row][j]));
        float gv = tanhf(gsm[2][row][j]);
        float ov = 1.f / (1.f + expf(-gsm[3][row][j]));
        float cn = fv * cs[row][j] + iv * gv;
        cs[row][j] = cn;
        float hn = ov * tanhf(cn);
        hs[pb ^ 1][row][j] = hn;
        if (t == T_ - 1)
          out[(size_t)(b0 + row) * C_ + j] = hn;    // code_vec, FLOAT32
      }
    }
    pb ^= 1;
    __syncthreads();
  }

  // ---------------- decoder ----------------
  const float brD[2] = { bih_d[g0] + bhh_d[g0], bih_d[g0 + 1] + bhh_d[g0 + 1] };
  const size_t SEQ0 = (size_t)B_ * C_;

  for (int t = 0; t < T_; ++t) {
    f32x4 acc[2][4];
    #pragma unroll
    for (int u = 0; u < 2; ++u)
      #pragma unroll
      for (int row = 0; row < 4; ++row) acc[u][row] = (f32x4){0.f, 0.f, 0.f, 0.f};
    for (int k = 0; k < C_; k += 4) {
      f32x4 w0 = *(const f32x4*)(whh_d + (size_t)g0 * C_ + k);
      f32x4 w1 = *(const f32x4*)(whh_d + (size_t)(g0 + 1) * C_ + k);
      if (t > 0) {   // inp_t == h_{t-1} for t>=1; inp_0 == 0
        w0 += *(const f32x4*)(wih_d + (size_t)g0 * C_ + k);
        w1 += *(const f32x4*)(wih_d + (size_t)(g0 + 1) * C_ + k);
      }
      #pragma unroll
      for (int row = 0; row < 4; ++row) {
        f32x4 hv = *(const f32x4*)(&hs[pb][row][k]);
        acc[0][row] += w0 * hv;
        acc[1][row] += w1 * hv;
      }
    }
    #pragma unroll
    for (int u = 0; u < 2; ++u)
      #pragma unroll
      for (int row = 0; row < 4; ++row) {
        f32x4 a = acc[u][row];
        gsm[type][row][(g0 + u) & 255] = brD[u] + a[0] + a[1] + a[2] + a[3];
      }
    __syncthreads();

    if (tid < 128) {
      int row = tid >> 5, jb = tid & 31;
      #pragma unroll
      for (int v = 0; v < 8; ++v) {
        int j = jb * 8 + v;
        float iv = 1.f / (1.f + expf(-gsm[0][row][j]));
        float fv = 1.f / (1.f + expf(-gsm[1][row][j]));
        float gv = tanhf(gsm[2][row][j]);
        float ov = 1.f / (1.f + expf(-gsm[3][row][j]));
        float cn = fv * cs[row][j] + iv * gv;
        cs[row][j] = cn;
        hs[pb ^ 1][row][j] = ov * tanhf(cn);
      }
    }
    pb ^= 1;
    __syncthreads();

    if (tid < 128) {
      int row = tid >> 5, n = tid & 31;
      const f32x4* wr = (const f32x4*)(w_dec + (size_t)n * C_);
      f32x4 a = {0.f, 0.f, 0.f, 0.f};
      for (int q = 0; q < 64; ++q) a += wr[q] * *(const f32x4*)(&hs[pb][row][q * 4]);
      out[SEQ0 + ((size_t)(b0 + row) * T_ + t) * INCH + n] =
          b_dec[n] + a[0] + a[1] + a[2] + a[3];    // FLOAT32
    }
  }
}

extern "C" void kernel_launch(void* const* d_in, const int* in_sizes, int n_in,
                              void* d_out, int out_size, void* d_ws, size_t ws_size,
                              hipStream_t stream) {
  static const int expect[13] = {
      B_ * T_ * INCH, 8192, 256, 262144, 262144, 1024, 1024,
      262144, 262144, 1024, 1024, 8192, 32
  };
  int bad = (n_in == 13) ? -1 : 99;
  if (bad < 0) {
    for (int i = 0; i < 13; ++i)
      if (in_sizes[i] != expect[i]) { bad = i; break; }
  }
  if (bad < 0 && out_size != B_ * C_ + B_ * T_ * INCH) bad = 50;
  if (bad >= 0) {
    sentinel_kernel<<<256, 256, 0, stream>>>((float*)d_out, out_size,
                                             1000.f + 10.f * (float)bad);
    return;
  }

  tae_f32<<<128, 512, 0, stream>>>(
      (const float*)d_in[0],
      (const float*)d_in[1], (const float*)d_in[2],
      (const float*)d_in[3], (const float*)d_in[4],
      (const float*)d_in[5], (const float*)d_in[6],
      (const float*)d_in[7], (const float*)d_in[8],
      (const float*)d_in[9], (const float*)d_in[10],
      (const float*)d_in[11], (const float*)d_in[12],
      (float*)d_out);
}

// Round 16
// 5043.840 us; speedup vs baseline: 7.3010x; 7.3010x over previous
//
#include <hip/hip_runtime.h>
#include <hip/hip_bf16.h>

#define B_    512
#define T_    256
#define INCH  32
#define C_    256

typedef __bf16 bf16_t;
typedef bf16_t bf16x8 __attribute__((ext_vector_type(8)));
typedef float  f32x4  __attribute__((ext_vector_type(4)));

// Workspace layout (bytes)
#define OFF_WHHE 0          // whh_e packed: 512KB
#define OFF_WCMB 524288     // (wih_d+whh_d) packed: 512KB
#define OFF_WHHD 1048576    // whh_d packed: 512KB
#define OFF_WIN  1572864    // W_in = wih_e@w_enc packed bf16: 64KB
#define OFF_WDEC 1638400    // w_dec packed bf16: 16KB
#define OFF_BE   1654784    // b_e[1024] f32 (bias + wih_e@b_enc fold)
#define OFF_BD   1658880    // b_d[1024] f32
#define WS_NEED  1662976

__device__ __forceinline__ float sigf(float x) {
  float e = exp2f(-1.4426950408889634f * x);
  return __builtin_amdgcn_rcpf(1.0f + e);
}
__device__ __forceinline__ float tanh_fast(float x) {
  float e = exp2f(2.8853900817779268f * x);
  return 1.0f - 2.0f * __builtin_amdgcn_rcpf(1.0f + e);
}

// ---- pack whh_e, wcomb=wih_d+whh_d, whh_d into MFMA-B fragment order.
// Block (nt,kt) = 1KB; lane l holds 8 contiguous bf16 = W[nt*16+(l&15)][kt*32+(l>>4)*8 ..)
__global__ void prep_pack_big(const float* __restrict__ whh_e,
                              const float* __restrict__ wih_d,
                              const float* __restrict__ whh_d,
                              char* __restrict__ ws) {
  int t = blockIdx.x * blockDim.x + threadIdx.x;   // 0..98303
  int m   = t >> 15;           // 0..2
  int r   = t & 32767;
  int blk = r >> 6;            // nt*8+kt
  int l   = r & 63;
  int nt  = blk >> 3, kt = blk & 7;
  int g   = nt * 16 + (l & 15);
  int k0  = kt * 32 + (l >> 4) * 8;
  const float* s0; const float* s1 = nullptr; char* dst;
  if (m == 0)      { s0 = whh_e; dst = ws + OFF_WHHE; }
  else if (m == 1) { s0 = wih_d; s1 = whh_d; dst = ws + OFF_WCMB; }
  else             { s0 = whh_d; dst = ws + OFF_WHHD; }
  bf16x8 v;
  #pragma unroll
  for (int i = 0; i < 8; ++i) {
    float a = s0[(size_t)g * C_ + k0 + i];
    if (s1) a += s1[(size_t)g * C_ + k0 + i];
    v[i] = (bf16_t)a;
  }
  *(bf16x8*)(dst + (size_t)blk * 1024 + l * 16) = v;
}

// ---- W_in = wih_e@w_enc packed, w_dec packed, fused biases
__global__ void prep_small(const float* __restrict__ w_enc,
                           const float* __restrict__ b_enc,
                           const float* __restrict__ wih_e,
                           const float* __restrict__ bih_e,
                           const float* __restrict__ bhh_e,
                           const float* __restrict__ bih_d,
                           const float* __restrict__ bhh_d,
                           const float* __restrict__ w_dec,
                           char* __restrict__ ws) {
  int t = blockIdx.x * blockDim.x + threadIdx.x;   // 0..43007
  if (t < 32768) {
    int nt = t >> 9;
    int r  = t & 511;
    int l  = r >> 3;
    int i  = r & 7;
    int g  = nt * 16 + (l & 15);
    int j  = (l >> 4) * 8 + i;
    float s = 0.f;
    for (int c = 0; c < C_; ++c)
      s += wih_e[(size_t)g * C_ + c] * w_enc[(size_t)c * INCH + j];
    ((bf16_t*)(ws + OFF_WIN))[(size_t)nt * 512 + l * 8 + i] = (bf16_t)s;
  } else if (t < 32768 + 8192) {
    int r   = t - 32768;
    int blk = r >> 9;
    int q   = r & 511;
    int l   = q >> 3;
    int i   = q & 7;
    int ntv = blk >> 3, kt = blk & 7;
    int n   = ntv * 16 + (l & 15);
    int k   = kt * 32 + (l >> 4) * 8 + i;
    ((bf16_t*)(ws + OFF_WDEC))[(size_t)blk * 512 + l * 8 + i] =
        (bf16_t)w_dec[(size_t)n * C_ + k];
  } else if (t < 32768 + 8192 + 1024) {
    int g = t - 40960;
    float s = bih_e[g] + bhh_e[g];
    for (int c = 0; c < C_; ++c) s += wih_e[(size_t)g * C_ + c] * b_enc[c];
    ((float*)(ws + OFF_BE))[g] = s;
  } else if (t < 43008) {
    int g = t - 41984;
    ((float*)(ws + OFF_BD))[g] = bih_d[g] + bhh_d[g];
  }
}

// ---- persistent MFMA kernel: 32 wgs x 512 thr (8 waves, 2/SIMD); wg owns 16 rows.
__global__ __launch_bounds__(512, 2) void tae_persist(
    const float* __restrict__ x,            // [B,T,32] f32
    const char*  __restrict__ ws,
    const float* __restrict__ b_dec,        // [32] f32
    float* __restrict__ out)                // f32: code [B,256] ++ recon [B,T,32]
{
  const bf16_t* __restrict__ whhE  = (const bf16_t*)(ws + OFF_WHHE);
  const bf16_t* __restrict__ wCMB  = (const bf16_t*)(ws + OFF_WCMB);
  const bf16_t* __restrict__ whhD  = (const bf16_t*)(ws + OFF_WHHD);
  const bf16_t* __restrict__ winP  = (const bf16_t*)(ws + OFF_WIN);
  const bf16_t* __restrict__ wdecP = (const bf16_t*)(ws + OFF_WDEC);
  const float*  __restrict__ bE    = (const float*)(ws + OFF_BE);
  const float*  __restrict__ bD    = (const float*)(ws + OFF_BD);

  const int b0   = blockIdx.x * 16;
  const int tid  = threadIdx.x;
  const int lane = tid & 63;
  const int wv   = tid >> 6;      // 0..7
  const int fr   = lane & 15;     // A row (batch) on reads / D col (channel) on writes
  const int lg   = lane >> 4;     // 0..3
  const int jt0  = wv * 2;        // this wave's hidden-channel tiles

  // double-buffered h in bf16, XOR-swizzled rows of 512B
  __shared__ __align__(16) unsigned char hb[2][8192];
  {
    f32x4 z = {0.f, 0.f, 0.f, 0.f};
    ((f32x4*)hb[0])[tid] = z;     // zero hb[0]
  }
  __syncthreads();

  float creg[2][4];
  #pragma unroll
  for (int a2 = 0; a2 < 2; ++a2)
    #pragma unroll
    for (int q = 0; q < 4; ++q) creg[a2][q] = 0.f;

  float biasE[2][4], biasD[2][4];
  #pragma unroll
  for (int a2 = 0; a2 < 2; ++a2)
    #pragma unroll
    for (int g = 0; g < 4; ++g) {
      biasE[a2][g] = bE[g * C_ + (jt0 + a2) * 16 + fr];
      biasD[a2][g] = bD[g * C_ + (jt0 + a2) * 16 + fr];
    }

  int pb = 0;

  // ---------------- encoder ----------------
  for (int t = 0; t < T_; ++t) {
    bf16x8 ah[8];
    #pragma unroll
    for (int kt = 0; kt < 8; ++kt) {
      int off = fr * 512 + ((kt * 64 + lg * 16) ^ ((fr & 7) << 4));
      ah[kt] = *(const bf16x8*)(hb[pb] + off);
    }
    bf16x8 ax;
    {
      const float* xp = x + (((size_t)(b0 + fr)) * T_ + t) * INCH + lg * 8;
      f32x4 x0 = *(const f32x4*)xp;
      f32x4 x1 = *(const f32x4*)(xp + 4);
      #pragma unroll
      for (int i = 0; i < 4; ++i) { ax[i] = (bf16_t)x0[i]; ax[4 + i] = (bf16_t)x1[i]; }
    }
    f32x4 acc[2][4];
    #pragma unroll
    for (int a2 = 0; a2 < 2; ++a2) {
      #pragma unroll
      for (int g = 0; g < 4; ++g) {
        float bv = biasE[a2][g];
        f32x4 ac = {bv, bv, bv, bv};
        int nt = g * 16 + jt0 + a2;
        ac = __builtin_amdgcn_mfma_f32_16x16x32_bf16(
                 ax, *(const bf16x8*)(winP + (size_t)nt * 512 + lane * 8), ac, 0, 0, 0);
        const bf16_t* bp = whhE + (size_t)nt * 4096 + lane * 8;
        #pragma unroll
        for (int kt = 0; kt < 8; ++kt)
          ac = __builtin_amdgcn_mfma_f32_16x16x32_bf16(
                   ah[kt], *(const bf16x8*)(bp + kt * 512), ac, 0, 0, 0);
        acc[a2][g] = ac;
      }
    }
    const bool last = (t == T_ - 1);
    #pragma unroll
    for (int a2 = 0; a2 < 2; ++a2) {
      #pragma unroll
      for (int q = 0; q < 4; ++q) {
        float iv = sigf(acc[a2][0][q]);
        float fv = sigf(acc[a2][1][q]);
        float gv = tanh_fast(acc[a2][2][q]);
        float ov = sigf(acc[a2][3][q]);
        float cn = fv * creg[a2][q] + iv * gv;
        creg[a2][q] = cn;
        float hn = ov * tanh_fast(cn);
        int rb = lg * 4 + q;
        int j  = (jt0 + a2) * 16 + fr;
        int off = rb * 512 + ((j * 2) ^ ((rb & 7) << 4));
        *(bf16_t*)(hb[pb ^ 1] + off) = (bf16_t)hn;
        if (last) out[(size_t)(b0 + rb) * C_ + j] = hn;   // code_vec, f32
      }
    }
    pb ^= 1;
    __syncthreads();
  }

  // ---------------- decoder ----------------
  const float bdec = (wv < 2) ? b_dec[wv * 16 + fr] : 0.f;
  const size_t SEQ0 = (size_t)B_ * C_;

  for (int t = 0; t < T_; ++t) {
    bf16x8 ah[8];
    #pragma unroll
    for (int kt = 0; kt < 8; ++kt) {
      int off = fr * 512 + ((kt * 64 + lg * 16) ^ ((fr & 7) << 4));
      ah[kt] = *(const bf16x8*)(hb[pb] + off);
    }
    // projection of h_{t-1} (waves 0,1 own the 2 n-tiles of IN=32)
    if (wv < 2 && t > 0) {
      f32x4 ay = {bdec, bdec, bdec, bdec};
      const bf16_t* yp = wdecP + (size_t)wv * 4096 + lane * 8;
      #pragma unroll
      for (int kt = 0; kt < 8; ++kt)
        ay = __builtin_amdgcn_mfma_f32_16x16x32_bf16(
                 ah[kt], *(const bf16x8*)(yp + kt * 512), ay, 0, 0, 0);
      #pragma unroll
      for (int q = 0; q < 4; ++q) {
        int rb = lg * 4 + q;
        out[SEQ0 + ((size_t)(b0 + rb) * T_ + (t - 1)) * INCH + wv * 16 + fr] = ay[q];
      }
    }
    const bf16_t* wb = (t == 0) ? whhD : wCMB;   // t=0: inp==0 -> whh_d only
    f32x4 acc[2][4];
    #pragma unroll
    for (int a2 = 0; a2 < 2; ++a2) {
      #pragma unroll
      for (int g = 0; g < 4; ++g) {
        float bv = biasD[a2][g];
        f32x4 ac = {bv, bv, bv, bv};
        int nt = g * 16 + jt0 + a2;
        const bf16_t* bp = wb + (size_t)nt * 4096 + lane * 8;
        #pragma unroll
        for (int kt = 0; kt < 8; ++kt)
          ac = __builtin_amdgcn_mfma_f32_16x16x32_bf16(
                   ah[kt], *(const bf16x8*)(bp + kt * 512), ac, 0, 0, 0);
        acc[a2][g] = ac;
      }
    }
    #pragma unroll
    for (int a2 = 0; a2 < 2; ++a2) {
      #pragma unroll
      for (int q = 0; q < 4; ++q) {
        float iv = sigf(acc[a2][0][q]);
        float fv = sigf(acc[a2][1][q]);
        float gv = tanh_fast(acc[a2][2][q]);
        float ov = sigf(acc[a2][3][q]);
        float cn = fv * creg[a2][q] + iv * gv;
        creg[a2][q] = cn;
        float hn = ov * tanh_fast(cn);
        int rb = lg * 4 + q;
        int j  = (jt0 + a2) * 16 + fr;
        int off = rb * 512 + ((j * 2) ^ ((rb & 7) << 4));
        *(bf16_t*)(hb[pb ^ 1] + off) = (bf16_t)hn;
      }
    }
    pb ^= 1;
    __syncthreads();
  }

  // final projection of h_{255}
  if (wv < 2) {
    bf16x8 ah[8];
    #pragma unroll
    for (int kt = 0; kt < 8; ++kt) {
      int off = fr * 512 + ((kt * 64 + lg * 16) ^ ((fr & 7) << 4));
      ah[kt] = *(const bf16x8*)(hb[pb] + off);
    }
    f32x4 ay = {bdec, bdec, bdec, bdec};
    const bf16_t* yp = wdecP + (size_t)wv * 4096 + lane * 8;
    #pragma unroll
    for (int kt = 0; kt < 8; ++kt)
      ay = __builtin_amdgcn_mfma_f32_16x16x32_bf16(
               ah[kt], *(const bf16x8*)(yp + kt * 512), ay, 0, 0, 0);
    #pragma unroll
    for (int q = 0; q < 4; ++q) {
      int rb = lg * 4 + q;
      out[SEQ0 + ((size_t)(b0 + rb) * T_ + (T_ - 1)) * INCH + wv * 16 + fr] = ay[q];
    }
  }
}

// ---- fallback: the R15 verified all-f32 kernel (used only if ws too small) ----
__global__ __launch_bounds__(512) void tae_f32(
    const float* __restrict__ x,
    const float* __restrict__ w_enc, const float* __restrict__ b_enc,
    const float* __restrict__ wih_e, const float* __restrict__ whh_e,
    const float* __restrict__ bih_e, const float* __restrict__ bhh_e,
    const float* __restrict__ wih_d, const float* __restrict__ whh_d,
    const float* __restrict__ bih_d, const float* __restrict__ bhh_d,
    const float* __restrict__ w_dec, const float* __restrict__ b_dec,
    float* __restrict__ out)
{
  const int b0   = blockIdx.x * 4;
  const int tid  = threadIdx.x;
  const int g0   = tid * 2;
  const int type = g0 >> 8;

  __shared__ __align__(16) float hs[2][4][256];
  __shared__ __align__(16) float cs[4][256];
  __shared__ __align__(16) float xe[4][256];
  __shared__ __align__(16) float gsm[4][4][256];

  for (int i = tid; i < 1024; i += 512) { ((float*)hs)[i] = 0.f; ((float*)cs)[i] = 0.f; }
  __syncthreads();

  const float brE[2] = { bih_e[g0] + bhh_e[g0], bih_e[g0 + 1] + bhh_e[g0 + 1] };
  int pb = 0;

  for (int t = 0; t < T_; ++t) {
    #pragma unroll
    for (int u = 0; u < 2; ++u) {
      int item = g0 + u;
      int row = item >> 8, c = item & 255;
      const f32x4* wr = (const f32x4*)(w_enc + (size_t)c * INCH);
      const f32x4* xr = (const f32x4*)(x + ((size_t)(b0 + row) * T_ + t) * INCH);
      f32x4 a = {0.f, 0.f, 0.f, 0.f};
      #pragma unroll
      for (int q = 0; q < 8; ++q) a += wr[q] * xr[q];
      xe[row][c] = b_enc[c] + a[0] + a[1] + a[2] + a[3];
    }
    __syncthreads();
    f32x4 acc[2][4];
    #pragma unroll
    for (int u = 0; u < 2; ++u)
      #pragma unroll
      for (int row = 0; row < 4; ++row) acc[u][row] = (f32x4){0.f,0.f,0.f,0.f};
    for (int k = 0; k < C_; k += 4) {
      f32x4 wx0 = *(const f32x4*)(wih_e + (size_t)g0 * C_ + k);
      f32x4 wx1 = *(const f32x4*)(wih_e + (size_t)(g0 + 1) * C_ + k);
      f32x4 wh0 = *(const f32x4*)(whh_e + (size_t)g0 * C_ + k);
      f32x4 wh1 = *(const f32x4*)(whh_e + (size_t)(g0 + 1) * C_ + k);
      #pragma unroll
      for (int row = 0; row < 4; ++row) {
        f32x4 xv = *(const f32x4*)(&xe[row][k]);
        f32x4 hv = *(const f32x4*)(&hs[pb][row][k]);
        acc[0][row] += wx0 * xv + wh0 * hv;
        acc[1][row] += wx1 * xv + wh1 * hv;
      }
    }
    #pragma unroll
    for (int u = 0; u < 2; ++u)
      #pragma unroll
      for (int row = 0; row < 4; ++row) {
        f32x4 a = acc[u][row];
        gsm[type][row][(g0 + u) & 255] = brE[u] + a[0] + a[1] + a[2] + a[3];
      }
    __syncthreads();
    if (tid < 128) {
      int row = tid >> 5, jb = tid & 31;
      #pragma unroll
      for (int v = 0; v < 8; ++v) {
        int j = jb * 8 + v;
        float iv = 1.f/(1.f+expf(-gsm[0][row][j]));
        float fv = 1.f/(1.f+expf(-gsm[1][row][j]));
        float gv = tanhf(gsm[2][row][j]);
        float ov = 1.f/(1.f+expf(-gsm[3][row][j]));
        float cn = fv*cs[row][j] + iv*gv;
        cs[row][j] = cn;
        float hn = ov*tanhf(cn);
        hs[pb ^ 1][row][j] = hn;
        if (t == T_ - 1) out[(size_t)(b0 + row) * C_ + j] = hn;
      }
    }
    pb ^= 1;
    __syncthreads();
  }

  const float brD[2] = { bih_d[g0] + bhh_d[g0], bih_d[g0 + 1] + bhh_d[g0 + 1] };
  const size_t SEQ0 = (size_t)B_ * C_;

  for (int t = 0; t < T_; ++t) {
    f32x4 acc[2][4];
    #pragma unroll
    for (int u = 0; u < 2; ++u)
      #pragma unroll
      for (int row = 0; row < 4; ++row) acc[u][row] = (f32x4){0.f,0.f,0.f,0.f};
    for (int k = 0; k < C_; k += 4) {
      f32x4 w0 = *(const f32x4*)(whh_d + (size_t)g0 * C_ + k);
      f32x4 w1 = *(const f32x4*)(whh_d + (size_t)(g0 + 1) * C_ + k);
      if (t > 0) {
        w0 += *(const f32x4*)(wih_d + (size_t)g0 * C_ + k);
        w1 += *(const f32x4*)(wih_d + (size_t)(g0 + 1) * C_ + k);
      }
      #pragma unroll
      for (int row = 0; row < 4; ++row) {
        f32x4 hv = *(const f32x4*)(&hs[pb][row][k]);
        acc[0][row] += w0 * hv;
        acc[1][row] += w1 * hv;
      }
    }
    #pragma unroll
    for (int u = 0; u < 2; ++u)
      #pragma unroll
      for (int row = 0; row < 4; ++row) {
        f32x4 a = acc[u][row];
        gsm[type][row][(g0 + u) & 255] = brD[u] + a[0] + a[1] + a[2] + a[3];
      }
    __syncthreads();
    if (tid < 128) {
      int row = tid >> 5, jb = tid & 31;
      #pragma unroll
      for (int v = 0; v < 8; ++v) {
        int j = jb * 8 + v;
        float iv = 1.f/(1.f+expf(-gsm[0][row][j]));
        float fv = 1.f/(1.f+expf(-gsm[1][row][j]));
        float gv = tanhf(gsm[2][row][j]);
        float ov = 1.f/(1.f+expf(-gsm[3][row][j]));
        float cn = fv*cs[row][j] + iv*gv;
        cs[row][j] = cn;
        hs[pb ^ 1][row][j] = ov*tanhf(cn);
      }
    }
    pb ^= 1;
    __syncthreads();
    if (tid < 128) {
      int row = tid >> 5, n = tid & 31;
      const f32x4* wr = (const f32x4*)(w_dec + (size_t)n * C_);
      f32x4 a = {0.f, 0.f, 0.f, 0.f};
      for (int q = 0; q < 64; ++q) a += wr[q] * *(const f32x4*)(&hs[pb][row][q * 4]);
      out[SEQ0 + ((size_t)(b0 + row) * T_ + t) * INCH + n] =
          b_dec[n] + a[0] + a[1] + a[2] + a[3];
    }
  }
}

extern "C" void kernel_launch(void* const* d_in, const int* in_sizes, int n_in,
                              void* d_out, int out_size, void* d_ws, size_t ws_size,
                              hipStream_t stream) {
  const float* x     = (const float*)d_in[0];
  const float* w_enc = (const float*)d_in[1];
  const float* b_enc = (const float*)d_in[2];
  const float* wih_e = (const float*)d_in[3];
  const float* whh_e = (const float*)d_in[4];
  const float* bih_e = (const float*)d_in[5];
  const float* bhh_e = (const float*)d_in[6];
  const float* wih_d = (const float*)d_in[7];
  const float* whh_d = (const float*)d_in[8];
  const float* bih_d = (const float*)d_in[9];
  const float* bhh_d = (const float*)d_in[10];
  const float* w_dec = (const float*)d_in[11];
  const float* b_dec = (const float*)d_in[12];

  if (ws_size >= WS_NEED) {
    char* ws = (char*)d_ws;
    prep_pack_big<<<384, 256, 0, stream>>>(whh_e, wih_d, whh_d, ws);
    prep_small<<<168, 256, 0, stream>>>(w_enc, b_enc, wih_e, bih_e, bhh_e,
                                        bih_d, bhh_d, w_dec, ws);
    tae_persist<<<32, 512, 0, stream>>>(x, ws, b_dec, (float*)d_out);
  } else {
    tae_f32<<<128, 512, 0, stream>>>(x, w_enc, b_enc, wih_e, whh_e, bih_e, bhh_e,
                                     wih_d, whh_d, bih_d, bhh_d, w_dec, b_dec,
                                     (float*)d_out);
  }
}